// Round 1
// baseline (286.931 us; speedup 1.0000x reference)
//
#include <hip/hip_runtime.h>
#include <math.h>

// Problem constants
#define B_ 4
#define N_ 20000
#define M_ 1024
#define K_ 16384
#define D_ 768

// Workspace layout (bytes). Total ~16.8 MB.
// fused [B][M][512] aliases xln [B][M][768] (xln dead after gemm1; transpose runs after gemm1).
// h2 [B][M][256] aliases h1 (h1 dead after gemm2).
#define OFF_CS   0ul
#define OFF_IDX  256ul
#define OFF_XLN  16640ul
#define OFF_H1   (OFF_XLN + 4ul*1024*768*4)   // 12599552

// ---------------------------------------------------------------------------
// Kernel 1: per-batch centroid + max-radius scale
__global__ __launch_bounds__(256) void k_centerscale(const float* __restrict__ pc,
                                                     float* __restrict__ cs)
{
    int b = blockIdx.x;
    const float* p = pc + (size_t)b * N_ * 3;
    int tid = threadIdx.x;
    float sx = 0.f, sy = 0.f, sz = 0.f;
    for (int i = tid; i < N_; i += 256) {
        sx += p[i*3+0]; sy += p[i*3+1]; sz += p[i*3+2];
    }
    __shared__ float red[3][4];
    __shared__ float cshare[3];
    for (int off = 32; off; off >>= 1) {
        sx += __shfl_down(sx, off, 64);
        sy += __shfl_down(sy, off, 64);
        sz += __shfl_down(sz, off, 64);
    }
    int wid = tid >> 6, lane = tid & 63;
    if (lane == 0) { red[0][wid] = sx; red[1][wid] = sy; red[2][wid] = sz; }
    __syncthreads();
    if (tid == 0) {
        cshare[0] = (red[0][0]+red[0][1]+red[0][2]+red[0][3]) / (float)N_;
        cshare[1] = (red[1][0]+red[1][1]+red[1][2]+red[1][3]) / (float)N_;
        cshare[2] = (red[2][0]+red[2][1]+red[2][2]+red[2][3]) / (float)N_;
    }
    __syncthreads();
    float cx = cshare[0], cy = cshare[1], cz = cshare[2];
    float mx = 0.f;
    for (int i = tid; i < N_; i += 256) {
        float dx = p[i*3+0]-cx, dy = p[i*3+1]-cy, dz = p[i*3+2]-cz;
        mx = fmaxf(mx, dx*dx + dy*dy + dz*dz);
    }
    for (int off = 32; off; off >>= 1) mx = fmaxf(mx, __shfl_down(mx, off, 64));
    if (lane == 0) red[0][wid] = mx;
    __syncthreads();
    if (tid == 0) {
        float m = fmaxf(fmaxf(red[0][0], red[0][1]), fmaxf(red[0][2], red[0][3]));
        cs[b*4+0] = cx; cs[b*4+1] = cy; cs[b*4+2] = cz;
        cs[b*4+3] = fmaxf(sqrtf(m), 1e-6f);
    }
}

// ---------------------------------------------------------------------------
// Kernel 2: NN argmin. Block = 16 seeds x 16 lanes; pts staged in LDS chunks.
// d2 = |s|^2 + |p|^2 - 2 s.p in normalized coords (matches reference formula).
__global__ __launch_bounds__(256) void k_nn(const float* __restrict__ seed_xyz,
                                            const float* __restrict__ pts,
                                            const float* __restrict__ cs,
                                            int* __restrict__ idx)
{
    __shared__ float4 P[256];
    int blk = blockIdx.x;
    int b = blk >> 6;
    int g = blk & 63;
    int tid = threadIdx.x;
    int j = tid & 15, s = tid >> 4;
    int m = g*16 + s;
    float cx = cs[b*4+0], cy = cs[b*4+1], cz = cs[b*4+2], sc = cs[b*4+3];
    const float* sp = seed_xyz + ((size_t)b*M_ + m)*3;
    float sx = (sp[0]-cx)/sc, sy = (sp[1]-cy)/sc, sz = (sp[2]-cz)/sc;
    float ssq = sx*sx + sy*sy + sz*sz;
    float best = 3.4e38f; int bestk = 0;
    const float* pb = pts + (size_t)b*K_*3;
    for (int c0 = 0; c0 < K_; c0 += 256) {
        const float* pp = pb + (size_t)(c0 + tid)*3;
        float px = (pp[0]-cx)/sc, py = (pp[1]-cy)/sc, pz = (pp[2]-cz)/sc;
        P[tid] = make_float4(px, py, pz, px*px + py*py + pz*pz);
        __syncthreads();
        #pragma unroll
        for (int kk = 0; kk < 16; ++kk) {
            int t = kk*16 + j;   // strided ownership: 2-way-bank-free LDS reads
            float4 q = P[t];
            float d2 = ssq + q.w - 2.f*(sx*q.x + sy*q.y + sz*q.z);
            int k = c0 + t;
            if (d2 < best) { best = d2; bestk = k; }
        }
        __syncthreads();
    }
    // reduce across the 16 lanes of this seed; tie -> smaller index (jnp.argmin)
    for (int mask = 8; mask; mask >>= 1) {
        float ob = __shfl_xor(best, mask, 64);
        int   ok = __shfl_xor(bestk, mask, 64);
        if (ob < best || (ob == best && ok < bestk)) { best = ob; bestk = ok; }
    }
    if (j == 0) idx[b*M_ + m] = bestk;
}

// ---------------------------------------------------------------------------
// Kernel 3: gather feat column at idx + LayerNorm over 768 channels.
// Block per (b,m); thread t owns channels {t, t+256, t+512}.
__global__ __launch_bounds__(256) void k_gather_ln(const float* __restrict__ feat,
                                                   const int* __restrict__ idx,
                                                   const float* __restrict__ gamma,
                                                   const float* __restrict__ beta,
                                                   float* __restrict__ xln)
{
    int bm = blockIdx.x;
    int b = bm >> 10;
    int tid = threadIdx.x;
    int id = idx[bm];
    const float* fb = feat + (size_t)b * D_ * K_ + id;
    float v[3];
    float s = 0.f, q = 0.f;
    #pragma unroll
    for (int r = 0; r < 3; ++r) {
        float x = fb[(size_t)(r*256 + tid) * K_];
        v[r] = x; s += x; q += x*x;
    }
    for (int off = 32; off; off >>= 1) {
        s += __shfl_down(s, off, 64);
        q += __shfl_down(q, off, 64);
    }
    __shared__ float red[2][4];
    int wid = tid >> 6, lane = tid & 63;
    if (lane == 0) { red[0][wid] = s; red[1][wid] = q; }
    __syncthreads();
    if (tid == 0) {
        red[0][0] = red[0][0]+red[0][1]+red[0][2]+red[0][3];
        red[1][0] = red[1][0]+red[1][1]+red[1][2]+red[1][3];
    }
    __syncthreads();
    s = red[0][0]; q = red[1][0];
    float mu  = s * (1.f/768.f);
    float var = q * (1.f/768.f) - mu*mu;
    float inv = rsqrtf(var + 1e-5f);
    float* orow = xln + (size_t)bm * D_;
    #pragma unroll
    for (int r = 0; r < 3; ++r) {
        int c = r*256 + tid;
        orow[c] = (v[r]-mu)*inv*gamma[c] + beta[c];
    }
}

// ---------------------------------------------------------------------------
// Kernel 4: transpose seed_features [B][256][M] -> fused[b][m][c] (c<256, row stride 512)
__global__ void k_transpose(const float* __restrict__ sf, float* __restrict__ fused)
{
    __shared__ float tile[32][33];
    int b  = blockIdx.z;
    int m0 = blockIdx.x * 32;
    int c0 = blockIdx.y * 32;
    int tx = threadIdx.x, ty = threadIdx.y;  // (32,8)
    #pragma unroll
    for (int r = 0; r < 32; r += 8)
        tile[ty+r][tx] = sf[((size_t)b*256 + c0+ty+r)*M_ + m0 + tx];
    __syncthreads();
    #pragma unroll
    for (int r = 0; r < 32; r += 8)
        fused[((size_t)b*M_ + m0+ty+r)*512 + c0 + tx] = tile[tx][ty+r];
}

// ---------------------------------------------------------------------------
// Kernel 5: tiled fp32 GEMM.  Y = act(W @ X^T + bias)
// X: [B][M][C] (row-major per m), W: [O][C], 64x64 output tile, K-chunk 16,
// LDS stored transposed [k][o]/[k][m] (+4 pad keeps 16B alignment) so the
// inner loop is 2x ds_read_b128 + 16 fma.
// mode 0: Y[b][m][rowStride] at colOff ([B][M][S]) ; mode 1: Y[b][o][m] ([B][O][M])
__global__ __launch_bounds__(256) void k_gemm(const float* __restrict__ X,
                                              const float* __restrict__ W,
                                              const float* __restrict__ bias,
                                              float* __restrict__ Y,
                                              int M, int C, int O,
                                              int relu, int mode,
                                              int rowStride, int colOff)
{
    __shared__ float Wl[16][68];
    __shared__ float Xl[16][68];
    int b  = blockIdx.z;
    int m0 = blockIdx.x * 64;
    int o0 = blockIdx.y * 64;
    int tid = threadIdx.x;
    int tm = tid & 15, to = tid >> 4;
    int lr = tid >> 2;
    int lc = (tid & 3) << 2;
    const float* Xb = X + (size_t)b * M * C;
    const float* wp = W  + (size_t)(o0 + lr) * C + lc;
    const float* xp = Xb + (size_t)(m0 + lr) * C + lc;
    float acc[4][4] = {{0.f}};
    for (int c0 = 0; c0 < C; c0 += 16) {
        float4 wv = *(const float4*)(wp + c0);
        float4 xv = *(const float4*)(xp + c0);
        __syncthreads();
        Wl[lc+0][lr] = wv.x; Wl[lc+1][lr] = wv.y; Wl[lc+2][lr] = wv.z; Wl[lc+3][lr] = wv.w;
        Xl[lc+0][lr] = xv.x; Xl[lc+1][lr] = xv.y; Xl[lc+2][lr] = xv.z; Xl[lc+3][lr] = xv.w;
        __syncthreads();
        #pragma unroll
        for (int k = 0; k < 16; ++k) {
            float4 wr = *(const float4*)&Wl[k][to << 2];
            float4 xr = *(const float4*)&Xl[k][tm << 2];
            float wa[4] = {wr.x, wr.y, wr.z, wr.w};
            float xa[4] = {xr.x, xr.y, xr.z, xr.w};
            #pragma unroll
            for (int i = 0; i < 4; ++i)
                #pragma unroll
                for (int jj = 0; jj < 4; ++jj)
                    acc[i][jj] = fmaf(wa[i], xa[jj], acc[i][jj]);
        }
    }
    int ob = o0 + (to << 2);
    int mb = m0 + (tm << 2);
    float4 bi = *(const float4*)&bias[ob];
    if (mode == 0) {
        #pragma unroll
        for (int jj = 0; jj < 4; ++jj) {
            float4 v;
            v.x = acc[0][jj] + bi.x; v.y = acc[1][jj] + bi.y;
            v.z = acc[2][jj] + bi.z; v.w = acc[3][jj] + bi.w;
            if (relu) {
                v.x = fmaxf(v.x, 0.f); v.y = fmaxf(v.y, 0.f);
                v.z = fmaxf(v.z, 0.f); v.w = fmaxf(v.w, 0.f);
            }
            *(float4*)&Y[((size_t)b*M + mb + jj)*rowStride + colOff + ob] = v;
        }
    } else {
        float bia[4] = {bi.x, bi.y, bi.z, bi.w};
        #pragma unroll
        for (int ii = 0; ii < 4; ++ii) {
            float4 v;
            v.x = acc[ii][0] + bia[ii]; v.y = acc[ii][1] + bia[ii];
            v.z = acc[ii][2] + bia[ii]; v.w = acc[ii][3] + bia[ii];
            if (relu) {
                v.x = fmaxf(v.x, 0.f); v.y = fmaxf(v.y, 0.f);
                v.z = fmaxf(v.z, 0.f); v.w = fmaxf(v.w, 0.f);
            }
            *(float4*)&Y[((size_t)b*O + ob + ii)*M + mb] = v;
        }
    }
}

// ---------------------------------------------------------------------------
extern "C" void kernel_launch(void* const* d_in, const int* in_sizes, int n_in,
                              void* d_out, int out_size, void* d_ws, size_t ws_size,
                              hipStream_t stream)
{
    (void)in_sizes; (void)n_in; (void)out_size; (void)ws_size;
    const float* pc        = (const float*)d_in[0];
    const float* seed_xyz  = (const float*)d_in[1];
    const float* seed_feat = (const float*)d_in[2];
    const float* pts       = (const float*)d_in[3];
    const float* feat      = (const float*)d_in[4];
    const float* ln_g      = (const float*)d_in[5];
    const float* ln_b      = (const float*)d_in[6];
    const float* pw1       = (const float*)d_in[7];
    const float* pb1       = (const float*)d_in[8];
    const float* pw2       = (const float*)d_in[9];
    const float* pb2       = (const float*)d_in[10];
    const float* fw1       = (const float*)d_in[11];
    const float* fb1       = (const float*)d_in[12];
    const float* fw2       = (const float*)d_in[13];
    const float* fb2       = (const float*)d_in[14];
    float* out = (float*)d_out;

    char* ws = (char*)d_ws;
    float* cs    = (float*)(ws + OFF_CS);
    int*   idx   = (int*)  (ws + OFF_IDX);
    float* xln   = (float*)(ws + OFF_XLN);   // [B][M][768]
    float* fused = (float*)(ws + OFF_XLN);   // [B][M][512] (aliases xln; safe by ordering)
    float* h1    = (float*)(ws + OFF_H1);    // [B][M][256]
    float* h2    = (float*)(ws + OFF_H1);    // [B][M][256] (aliases h1; safe by ordering)

    k_centerscale<<<B_, 256, 0, stream>>>(pc, cs);
    k_nn<<<B_*(M_/16), 256, 0, stream>>>(seed_xyz, pts, cs, idx);
    k_gather_ln<<<B_*M_, 256, 0, stream>>>(feat, idx, ln_g, ln_b, xln);
    // gemm1: h1 = relu(pw1 @ xln + pb1)   [B][M][256]
    k_gemm<<<dim3(M_/64, 256/64, B_), 256, 0, stream>>>(xln, pw1, pb1, h1,
                                                        M_, 768, 256, 1, 0, 256, 0);
    // fill fused[:, :, 0:256] = seed_features^T  (after gemm1: fused aliases xln)
    k_transpose<<<dim3(M_/32, 256/32, B_), dim3(32, 8), 0, stream>>>(seed_feat, fused);
    // gemm2: fused[:, :, 256:512] = pw2 @ h1 + pb2
    k_gemm<<<dim3(M_/64, 256/64, B_), 256, 0, stream>>>(h1, pw2, pb2, fused,
                                                        M_, 256, 256, 0, 0, 512, 256);
    // gemm3: h2 = relu(fw1 @ fused + fb1)
    k_gemm<<<dim3(M_/64, 256/64, B_), 256, 0, stream>>>(fused, fw1, fb1, h2,
                                                        M_, 512, 256, 1, 0, 256, 0);
    // gemm4: out = fw2 @ h2 + fb2   -> [B][256][M] (reference layout)
    k_gemm<<<dim3(M_/64, 256/64, B_), 256, 0, stream>>>(h2, fw2, fb2, out,
                                                        M_, 256, 256, 0, 1, 0, 0);
}

// Round 2
// 206.568 us; speedup vs baseline: 1.3890x; 1.3890x over previous
//
#include <hip/hip_runtime.h>
#include <math.h>

#define B_ 4
#define N_ 20000
#define M_ 1024
#define K_ 16384
#define D_ 768

typedef __attribute__((ext_vector_type(8))) short bf16x8;
typedef __attribute__((ext_vector_type(4))) float f32x4;

// Workspace offsets (ws is 768 MiB; no aliasing needed)
#define OFF_CS     0ul
#define OFF_IDX    1024ul
#define OFF_STATS  32768ul        // float2[4096]
#define OFF_G      65536ul        // f32 [4][768][1024] = 12.58 MB
#define OFF_XLN    16777216ul     // bf16 [4096][768]   = 6.29 MB
#define OFF_H1     25165824ul     // bf16 [4096][256]
#define OFF_FUSED  28311552ul     // bf16 [4096][512]
#define OFF_H2     33554432ul     // bf16 [4096][256]
#define OFF_WB1    36700160ul     // bf16 256x768
#define OFF_WB2    37748736ul     // bf16 256x256
#define OFF_WB3    38797312ul     // bf16 256x512
#define OFF_WB4    39845888ul     // bf16 256x256

__device__ inline unsigned short f2bf(float x) {
    union { float f; unsigned int u; } v; v.f = x;
    unsigned int r = v.u + 0x7fffu + ((v.u >> 16) & 1u);
    return (unsigned short)(r >> 16);
}

__device__ inline void gload_lds16(const void* g, void* lds) {
    __builtin_amdgcn_global_load_lds(
        (const __attribute__((address_space(1))) unsigned int*)g,
        (__attribute__((address_space(3))) unsigned int*)lds, 16, 0, 0);
}

// ---------------------------------------------------------------------------
// centroid + max-radius scale, one block per batch
__global__ __launch_bounds__(256) void k_centerscale(const float* __restrict__ pc,
                                                     float* __restrict__ cs)
{
    int b = blockIdx.x;
    const float* p = pc + (size_t)b * N_ * 3;
    int tid = threadIdx.x;
    float sx = 0.f, sy = 0.f, sz = 0.f;
    for (int i = tid; i < N_; i += 256) {
        sx += p[i*3+0]; sy += p[i*3+1]; sz += p[i*3+2];
    }
    __shared__ float red[3][4];
    __shared__ float cshare[3];
    for (int off = 32; off; off >>= 1) {
        sx += __shfl_down(sx, off, 64);
        sy += __shfl_down(sy, off, 64);
        sz += __shfl_down(sz, off, 64);
    }
    int wid = tid >> 6, lane = tid & 63;
    if (lane == 0) { red[0][wid] = sx; red[1][wid] = sy; red[2][wid] = sz; }
    __syncthreads();
    if (tid == 0) {
        cshare[0] = (red[0][0]+red[0][1]+red[0][2]+red[0][3]) / (float)N_;
        cshare[1] = (red[1][0]+red[1][1]+red[1][2]+red[1][3]) / (float)N_;
        cshare[2] = (red[2][0]+red[2][1]+red[2][2]+red[2][3]) / (float)N_;
    }
    __syncthreads();
    float cx = cshare[0], cy = cshare[1], cz = cshare[2];
    float mx = 0.f;
    for (int i = tid; i < N_; i += 256) {
        float dx = p[i*3+0]-cx, dy = p[i*3+1]-cy, dz = p[i*3+2]-cz;
        mx = fmaxf(mx, dx*dx + dy*dy + dz*dz);
    }
    for (int off = 32; off; off >>= 1) mx = fmaxf(mx, __shfl_down(mx, off, 64));
    if (lane == 0) red[0][wid] = mx;
    __syncthreads();
    if (tid == 0) {
        float m = fmaxf(fmaxf(red[0][0], red[0][1]), fmaxf(red[0][2], red[0][3]));
        cs[b*4+0] = cx; cs[b*4+1] = cy; cs[b*4+2] = cz;
        cs[b*4+3] = fmaxf(sqrtf(m), 1e-6f);
    }
}

// ---------------------------------------------------------------------------
// NN argmin; block = 16 seeds x 16 lanes; pts chunks in LDS
__global__ __launch_bounds__(256) void k_nn(const float* __restrict__ seed_xyz,
                                            const float* __restrict__ pts,
                                            const float* __restrict__ cs,
                                            int* __restrict__ idx)
{
    __shared__ float4 P[256];
    int blk = blockIdx.x;
    int b = blk >> 6;
    int g = blk & 63;
    int tid = threadIdx.x;
    int j = tid & 15, s = tid >> 4;
    int m = g*16 + s;
    float cx = cs[b*4+0], cy = cs[b*4+1], cz = cs[b*4+2], sc = cs[b*4+3];
    const float* sp = seed_xyz + ((size_t)b*M_ + m)*3;
    float sx = (sp[0]-cx)/sc, sy = (sp[1]-cy)/sc, sz = (sp[2]-cz)/sc;
    float ssq = sx*sx + sy*sy + sz*sz;
    float best = 3.4e38f; int bestk = 0;
    const float* pb = pts + (size_t)b*K_*3;
    for (int c0 = 0; c0 < K_; c0 += 256) {
        const float* pp = pb + (size_t)(c0 + tid)*3;
        float px = (pp[0]-cx)/sc, py = (pp[1]-cy)/sc, pz = (pp[2]-cz)/sc;
        P[tid] = make_float4(px, py, pz, px*px + py*py + pz*pz);
        __syncthreads();
        #pragma unroll
        for (int kk = 0; kk < 16; ++kk) {
            int tt = kk*16 + j;
            float4 q = P[tt];
            float d2 = ssq + q.w - 2.f*(sx*q.x + sy*q.y + sz*q.z);
            int k = c0 + tt;
            if (d2 < best) { best = d2; bestk = k; }
        }
        __syncthreads();
    }
    for (int mask = 8; mask; mask >>= 1) {
        float ob = __shfl_xor(best, mask, 64);
        int   ok = __shfl_xor(bestk, mask, 64);
        if (ob < best || (ob == best && ok < bestk)) { best = ob; bestk = ok; }
    }
    if (j == 0) idx[b*M_ + m] = bestk;
}

// ---------------------------------------------------------------------------
// gather: block per (b,c) row; 1024 scattered reads within one 64KB row
// (line reuse in L1/L2), coalesced writes G[b][c][m]
__global__ __launch_bounds__(256) void k_gather(const float* __restrict__ feat,
                                                const int* __restrict__ idx,
                                                float* __restrict__ G)
{
    int c = blockIdx.x, b = blockIdx.y;
    int t = threadIdx.x;
    const float* frow = feat + ((size_t)b*D_ + c) * K_;
    const int* ib = idx + b*M_;
    float* grow = G + ((size_t)b*D_ + c) * M_;
    #pragma unroll
    for (int r = 0; r < 4; ++r) {
        int m = r*256 + t;
        grow[m] = frow[ib[m]];
    }
}

// ---------------------------------------------------------------------------
// LN stats: block covers 128 m (lane owns m-pair), coalesced float2 reads over c
__global__ __launch_bounds__(256) void k_ln_stats(const float* __restrict__ G,
                                                  float2* __restrict__ stats)
{
    int b = blockIdx.y, m0 = blockIdx.x * 128;
    int t = threadIdx.x, l = t & 63, w = t >> 6;
    const float* Gb = G + (size_t)b * D_ * M_;
    float s0=0.f,q0=0.f,s1=0.f,q1=0.f;
    for (int c = w*192; c < w*192 + 192; ++c) {
        float2 v = *(const float2*)&Gb[(size_t)c*M_ + m0 + l*2];
        s0 += v.x; q0 += v.x*v.x;
        s1 += v.y; q1 += v.y*v.y;
    }
    __shared__ float red[4][64][4];
    red[w][l][0]=s0; red[w][l][1]=q0; red[w][l][2]=s1; red[w][l][3]=q1;
    __syncthreads();
    if (w == 0) {
        float S0=0,Q0=0,S1=0,Q1=0;
        #pragma unroll
        for (int ww = 0; ww < 4; ++ww) {
            S0+=red[ww][l][0]; Q0+=red[ww][l][1];
            S1+=red[ww][l][2]; Q1+=red[ww][l][3];
        }
        int m = m0 + l*2;
        float mu0 = S0*(1.f/768.f);
        float iv0 = rsqrtf(Q0*(1.f/768.f) - mu0*mu0 + 1e-5f);
        float mu1 = S1*(1.f/768.f);
        float iv1 = rsqrtf(Q1*(1.f/768.f) - mu1*mu1 + 1e-5f);
        stats[b*M_ + m]     = make_float2(mu0, iv0);
        stats[b*M_ + m + 1] = make_float2(mu1, iv1);
    }
}

// ---------------------------------------------------------------------------
// apply LN + transpose G[b][c][m] -> xln[b][m][c] (bf16), 32x32 LDS tiles
__global__ void k_ln_applyT(const float* __restrict__ G,
                            const float2* __restrict__ stats,
                            const float* __restrict__ gamma,
                            const float* __restrict__ beta,
                            unsigned short* __restrict__ xln)
{
    __shared__ float tile[32][33];
    int m0 = blockIdx.x*32, c0 = blockIdx.y*32, b = blockIdx.z;
    int tx = threadIdx.x, ty = threadIdx.y;
    const float* Gb = G + (size_t)b * D_ * M_;
    #pragma unroll
    for (int r = 0; r < 32; r += 8)
        tile[ty+r][tx] = Gb[(size_t)(c0+ty+r)*M_ + m0 + tx];
    __syncthreads();
    float ga = gamma[c0+tx], be = beta[c0+tx];
    #pragma unroll
    for (int r = 0; r < 32; r += 8) {
        int m = m0 + ty + r;
        float2 st = stats[b*M_ + m];
        float v = (tile[tx][ty+r] - st.x) * st.y * ga + be;
        xln[((size_t)(b*M_ + m))*D_ + c0 + tx] = f2bf(v);
    }
}

// ---------------------------------------------------------------------------
// seed_features [B][256][M] f32 -> fused[b][m][0:256] bf16 (row stride 512)
__global__ void k_transpose_sf(const float* __restrict__ sf,
                               unsigned short* __restrict__ fused)
{
    __shared__ float tile[32][33];
    int m0 = blockIdx.x*32, c0 = blockIdx.y*32, b = blockIdx.z;
    int tx = threadIdx.x, ty = threadIdx.y;
    #pragma unroll
    for (int r = 0; r < 32; r += 8)
        tile[ty+r][tx] = sf[((size_t)b*256 + c0+ty+r)*M_ + m0 + tx];
    __syncthreads();
    #pragma unroll
    for (int r = 0; r < 32; r += 8)
        fused[((size_t)(b*M_ + m0+ty+r))*512 + c0 + tx] = f2bf(tile[tx][ty+r]);
}

// ---------------------------------------------------------------------------
// convert weights to bf16
__global__ __launch_bounds__(256) void k_cvt_w(
    const float* __restrict__ w1, const float* __restrict__ w2,
    const float* __restrict__ w3, const float* __restrict__ w4,
    unsigned short* __restrict__ o1, unsigned short* __restrict__ o2,
    unsigned short* __restrict__ o3, unsigned short* __restrict__ o4)
{
    int i = blockIdx.x*256 + threadIdx.x;
    if (i < 256*768) o1[i] = f2bf(w1[i]);
    if (i < 256*256) o2[i] = f2bf(w2[i]);
    if (i < 256*512) o3[i] = f2bf(w3[i]);
    if (i < 256*256) o4[i] = f2bf(w4[i]);
}

// ---------------------------------------------------------------------------
// MFMA GEMM: C[m][o] = act( sum_k X[m][k] * W[o][k] + bias[o] )
// X bf16 [R=4096][K], W bf16 [O=256][K]. 64x64 tile, 4 waves; wave w owns
// m-rows [w*16, w*16+16) x all 64 o. K-chunk 64 staged via global_load_lds
// (linear LDS dest, pre-swizzled global source; readers use same XOR swizzle).
// mode 0: bf16 Y[m][rowStride] at colOff; mode 1: f32 out [B][256][1024].
__global__ __launch_bounds__(256) void k_gemm_mfma(
    const unsigned short* __restrict__ X, const unsigned short* __restrict__ W,
    const float* __restrict__ bias, int Kdim, int relu, int mode,
    unsigned short* __restrict__ Ybf, int rowStride, int colOff,
    float* __restrict__ Yf)
{
    __shared__ unsigned short Al[64*64];
    __shared__ unsigned short Wl[64*64];
    int t = threadIdx.x, l = t & 63, w = t >> 6;
    int m0 = blockIdx.x * 64, o0 = blockIdx.y * 64;
    f32x4 acc[4];
    #pragma unroll
    for (int j = 0; j < 4; ++j) acc[j] = (f32x4){0.f, 0.f, 0.f, 0.f};

    for (int kc = 0; kc < Kdim; kc += 64) {
        #pragma unroll
        for (int i = 0; i < 2; ++i) {
            int lin = i*4096 + w*1024;       // wave-uniform byte base within tile
            int lb  = lin + l*16;            // this lane's linear byte
            int row = lb >> 7;               // 128B per 64-bf16 row
            int k16 = (lb >> 4) & 7;
            int ks  = k16 ^ (row & 7);       // inverse-swizzled source granule
            gload_lds16(X + (size_t)(m0+row)*Kdim + kc + ks*8, (char*)Al + lin);
            gload_lds16(W + (size_t)(o0+row)*Kdim + kc + ks*8, (char*)Wl + lin);
        }
        __syncthreads();                     // drains vmcnt(0) before barrier
        #pragma unroll
        for (int kk = 0; kk < 2; ++kk) {
            int arow = w*16 + (l & 15);
            int h = l >> 4;
            bf16x8 a = *(const bf16x8*)&Al[arow*64 + (((kk<<2)|h) ^ (arow & 7))*8];
            #pragma unroll
            for (int j = 0; j < 4; ++j) {
                int orow = j*16 + (l & 15);
                bf16x8 bfr = *(const bf16x8*)&Wl[orow*64 + (((kk<<2)|h) ^ (orow & 7))*8];
                acc[j] = __builtin_amdgcn_mfma_f32_16x16x32_bf16(a, bfr, acc[j], 0, 0, 0);
            }
        }
        __syncthreads();
    }

    int mbase = m0 + w*16 + (l >> 4)*4;      // D row = (l>>4)*4 + reg
    if (mode == 0) {
        #pragma unroll
        for (int j = 0; j < 4; ++j) {
            int o = o0 + j*16 + (l & 15);    // D col = l&15
            float bi = bias[o];
            #pragma unroll
            for (int r = 0; r < 4; ++r) {
                float v = acc[j][r] + bi;
                if (relu) v = fmaxf(v, 0.f);
                Ybf[(size_t)(mbase + r)*rowStride + colOff + o] = f2bf(v);
            }
        }
    } else {
        int b = mbase >> 10, ml = mbase & 1023;
        #pragma unroll
        for (int j = 0; j < 4; ++j) {
            int o = o0 + j*16 + (l & 15);
            float bi = bias[o];
            float4 s = make_float4(acc[j][0]+bi, acc[j][1]+bi, acc[j][2]+bi, acc[j][3]+bi);
            *(float4*)&Yf[((size_t)(b*256 + o))*1024 + ml] = s;
        }
    }
}

// ---------------------------------------------------------------------------
extern "C" void kernel_launch(void* const* d_in, const int* in_sizes, int n_in,
                              void* d_out, int out_size, void* d_ws, size_t ws_size,
                              hipStream_t stream)
{
    (void)in_sizes; (void)n_in; (void)out_size; (void)ws_size;
    const float* pc        = (const float*)d_in[0];
    const float* seed_xyz  = (const float*)d_in[1];
    const float* seed_feat = (const float*)d_in[2];
    const float* pts       = (const float*)d_in[3];
    const float* feat      = (const float*)d_in[4];
    const float* ln_g      = (const float*)d_in[5];
    const float* ln_b      = (const float*)d_in[6];
    const float* pw1       = (const float*)d_in[7];
    const float* pb1       = (const float*)d_in[8];
    const float* pw2       = (const float*)d_in[9];
    const float* pb2       = (const float*)d_in[10];
    const float* fw1       = (const float*)d_in[11];
    const float* fb1       = (const float*)d_in[12];
    const float* fw2       = (const float*)d_in[13];
    const float* fb2       = (const float*)d_in[14];
    float* out = (float*)d_out;

    char* ws = (char*)d_ws;
    float*          cs    = (float*)(ws + OFF_CS);
    int*            idx   = (int*)(ws + OFF_IDX);
    float2*         stats = (float2*)(ws + OFF_STATS);
    float*          G     = (float*)(ws + OFF_G);
    unsigned short* xln   = (unsigned short*)(ws + OFF_XLN);
    unsigned short* h1    = (unsigned short*)(ws + OFF_H1);
    unsigned short* fused = (unsigned short*)(ws + OFF_FUSED);
    unsigned short* h2    = (unsigned short*)(ws + OFF_H2);
    unsigned short* Wb1   = (unsigned short*)(ws + OFF_WB1);
    unsigned short* Wb2   = (unsigned short*)(ws + OFF_WB2);
    unsigned short* Wb3   = (unsigned short*)(ws + OFF_WB3);
    unsigned short* Wb4   = (unsigned short*)(ws + OFF_WB4);

    k_cvt_w<<<768, 256, 0, stream>>>(pw1, pw2, fw1, fw2, Wb1, Wb2, Wb3, Wb4);
    k_centerscale<<<B_, 256, 0, stream>>>(pc, cs);
    k_nn<<<B_*(M_/16), 256, 0, stream>>>(seed_xyz, pts, cs, idx);
    k_gather<<<dim3(D_, B_), 256, 0, stream>>>(feat, idx, G);
    k_ln_stats<<<dim3(M_/128, B_), 256, 0, stream>>>(G, stats);
    k_ln_applyT<<<dim3(M_/32, D_/32, B_), dim3(32, 8), 0, stream>>>(G, stats, ln_g, ln_b, xln);
    // gemm1: h1 = relu(pw1 @ xln + pb1)
    k_gemm_mfma<<<dim3(64, 4), 256, 0, stream>>>(xln, Wb1, pb1, 768, 1, 0, h1, 256, 0, nullptr);
    k_transpose_sf<<<dim3(M_/32, 256/32, B_), dim3(32, 8), 0, stream>>>(seed_feat, fused);
    // gemm2: fused[:,256:512] = pw2 @ h1 + pb2
    k_gemm_mfma<<<dim3(64, 4), 256, 0, stream>>>(h1, Wb2, pb2, 256, 0, 0, fused, 512, 256, nullptr);
    // gemm3: h2 = relu(fw1 @ fused + fb1)
    k_gemm_mfma<<<dim3(64, 4), 256, 0, stream>>>(fused, Wb3, fb1, 512, 1, 0, h2, 256, 0, nullptr);
    // gemm4: out = fw2 @ h2 + fb2  -> f32 [B][256][M]
    k_gemm_mfma<<<dim3(64, 4), 256, 0, stream>>>(h2, Wb4, fb2, 256, 0, 1, nullptr, 0, 0, out);
}

// Round 3
// 164.731 us; speedup vs baseline: 1.7418x; 1.2540x over previous
//
#include <hip/hip_runtime.h>
#include <math.h>

#define B_ 4
#define N_ 20000
#define M_ 1024
#define K_ 16384
#define D_ 768

typedef __attribute__((ext_vector_type(8))) short bf16x8;
typedef __attribute__((ext_vector_type(4))) float f32x4;

// Workspace offsets (ws is 768 MiB)
#define OFF_PART   0ul          // f32 [4][16][3] partial sums
#define OFF_RAD    1024ul       // f32 [4][16] partial max radius^2
#define OFF_IDX    4096ul       // int [4][1024]
#define OFF_P4     32768ul      // float4 [4][16384] normalized pts  (1 MB)
#define OFF_G      2097152ul    // f32 [4][768][1024]  (12.58 MB)
#define OFF_XLN    16777216ul   // bf16 [4096][768]
#define OFF_FUSED  25165824ul   // bf16 [4096][512]
#define OFF_H2     29360128ul   // bf16 [4096][256]
#define OFF_WB1    33554432ul   // bf16 [256][768]
#define OFF_WCAT   34603008ul   // bf16 [256][512]
#define OFF_WB4    35651584ul   // bf16 [256][256]
#define OFF_BC     36700160ul   // f32 [256]

__device__ inline unsigned short f2bf(float x) {
    union { float f; unsigned int u; } v; v.f = x;
    unsigned int r = v.u + 0x7fffu + ((v.u >> 16) & 1u);
    return (unsigned short)(r >> 16);
}

__device__ inline void gload_lds16(const void* g, void* lds) {
    __builtin_amdgcn_global_load_lds(
        (const __attribute__((address_space(1))) unsigned int*)g,
        (__attribute__((address_space(3))) unsigned int*)lds, 16, 0, 0);
}

// ---------------------------------------------------------------------------
// Stage A: per-chunk partial sums of pc (64 blocks: 16 per batch x 1250 pts)
__global__ __launch_bounds__(256) void k_cs_sum(const float* __restrict__ pc,
                                                float* __restrict__ part)
{
    int blk = blockIdx.x, b = blk >> 4, pi = blk & 15;
    const float* p = pc + (size_t)b * N_ * 3;
    int tid = threadIdx.x;
    int i0 = pi * 1250;
    float sx = 0.f, sy = 0.f, sz = 0.f;
    for (int i = i0 + tid; i < i0 + 1250; i += 256) {
        sx += p[i*3+0]; sy += p[i*3+1]; sz += p[i*3+2];
    }
    for (int off = 32; off; off >>= 1) {
        sx += __shfl_down(sx, off, 64);
        sy += __shfl_down(sy, off, 64);
        sz += __shfl_down(sz, off, 64);
    }
    __shared__ float red[3][4];
    int w = tid >> 6, l = tid & 63;
    if (!l) { red[0][w] = sx; red[1][w] = sy; red[2][w] = sz; }
    __syncthreads();
    if (!tid) {
        part[(b*16+pi)*3+0] = red[0][0]+red[0][1]+red[0][2]+red[0][3];
        part[(b*16+pi)*3+1] = red[1][0]+red[1][1]+red[1][2]+red[1][3];
        part[(b*16+pi)*3+2] = red[2][0]+red[2][1]+red[2][2]+red[2][3];
    }
}

__device__ inline void reduce_center(const float* part, int b,
                                     float& cx, float& cy, float& cz)
{
    cx = 0.f; cy = 0.f; cz = 0.f;
    #pragma unroll
    for (int r = 0; r < 16; ++r) {
        cx += part[(b*16+r)*3+0];
        cy += part[(b*16+r)*3+1];
        cz += part[(b*16+r)*3+2];
    }
    cx *= (1.f/N_); cy *= (1.f/N_); cz *= (1.f/N_);
}

// Stage B: per-chunk partial max radius^2 (center reduced inline)
__global__ __launch_bounds__(256) void k_cs_rad(const float* __restrict__ pc,
                                                const float* __restrict__ part,
                                                float* __restrict__ rad)
{
    int blk = blockIdx.x, b = blk >> 4, pi = blk & 15;
    float cx, cy, cz;
    reduce_center(part, b, cx, cy, cz);
    const float* p = pc + (size_t)b * N_ * 3;
    int tid = threadIdx.x;
    int i0 = pi * 1250;
    float mx = 0.f;
    for (int i = i0 + tid; i < i0 + 1250; i += 256) {
        float dx = p[i*3+0]-cx, dy = p[i*3+1]-cy, dz = p[i*3+2]-cz;
        mx = fmaxf(mx, dx*dx + dy*dy + dz*dz);
    }
    for (int off = 32; off; off >>= 1) mx = fmaxf(mx, __shfl_down(mx, off, 64));
    __shared__ float red[4];
    int w = tid >> 6, l = tid & 63;
    if (!l) red[w] = mx;
    __syncthreads();
    if (!tid) rad[b*16+pi] = fmaxf(fmaxf(red[0], red[1]), fmaxf(red[2], red[3]));
}

__device__ inline float reduce_scale(const float* rad, int b)
{
    float m = 0.f;
    #pragma unroll
    for (int r = 0; r < 16; ++r) m = fmaxf(m, rad[b*16+r]);
    return fmaxf(sqrtf(m), 1e-6f);
}

// ---------------------------------------------------------------------------
// normalize pts -> float4(nx,ny,nz,|n|^2)   (256 blocks: 64 per batch)
__global__ __launch_bounds__(256) void k_prep_pts(const float* __restrict__ pts,
                                                  const float* __restrict__ part,
                                                  const float* __restrict__ rad,
                                                  float4* __restrict__ P4)
{
    int blk = blockIdx.x, b = blk >> 6;
    float cx, cy, cz;
    reduce_center(part, b, cx, cy, cz);
    float sc = 1.f / reduce_scale(rad, b);
    int k = (blk & 63)*256 + threadIdx.x;
    const float* pp = pts + ((size_t)b*K_ + k)*3;
    float px = (pp[0]-cx)*sc, py = (pp[1]-cy)*sc, pz = (pp[2]-cz)*sc;
    P4[(size_t)b*K_ + k] = make_float4(px, py, pz, px*px + py*py + pz*pz);
}

// ---------------------------------------------------------------------------
// NN argmin: 512 blocks; block = 8 seeds x 32 lanes, no LDS, no barriers.
__global__ __launch_bounds__(256) void k_nn(const float* __restrict__ seed_xyz,
                                            const float4* __restrict__ P4,
                                            const float* __restrict__ part,
                                            const float* __restrict__ rad,
                                            int* __restrict__ idx)
{
    int blk = blockIdx.x, b = blk >> 7, g = blk & 127;
    float cx, cy, cz;
    reduce_center(part, b, cx, cy, cz);
    float sc = 1.f / reduce_scale(rad, b);
    int t = threadIdx.x;
    int j = t & 31, s = t >> 5;
    int m = g*8 + s;
    const float* sp = seed_xyz + ((size_t)b*M_ + m)*3;
    float sx = (sp[0]-cx)*sc, sy = (sp[1]-cy)*sc, sz = (sp[2]-cz)*sc;
    float ssq = sx*sx + sy*sy + sz*sz;
    const float4* Pb = P4 + (size_t)b*K_;

    float best[4] = {3.4e38f, 3.4e38f, 3.4e38f, 3.4e38f};
    int   bk[4]   = {0, 0, 0, 0};
    for (int i = 0; i < 512; i += 4) {
        #pragma unroll
        for (int r = 0; r < 4; ++r) {
            int k = (i + r)*32 + j;
            float4 q = Pb[k];
            float d2 = ssq + q.w - 2.f*(sx*q.x + sy*q.y + sz*q.z);
            if (d2 < best[r]) { best[r] = d2; bk[r] = k; }
        }
    }
    float bm = best[0]; int bmk = bk[0];
    #pragma unroll
    for (int r = 1; r < 4; ++r) {
        if (best[r] < bm || (best[r] == bm && bk[r] < bmk)) { bm = best[r]; bmk = bk[r]; }
    }
    #pragma unroll
    for (int mask = 16; mask; mask >>= 1) {
        float ob = __shfl_xor(bm, mask, 64);
        int   ok = __shfl_xor(bmk, mask, 64);
        if (ob < bm || (ob == bm && ok < bmk)) { bm = ob; bmk = ok; }
    }
    if (j == 0) idx[b*M_ + m] = bmk;
}

// ---------------------------------------------------------------------------
// gather: block per (b,c) row; scattered reads in one 64KB row, coalesced write
__global__ __launch_bounds__(256) void k_gather(const float* __restrict__ feat,
                                                const int* __restrict__ idx,
                                                float* __restrict__ G)
{
    int c = blockIdx.x, b = blockIdx.y;
    int t = threadIdx.x;
    const float* frow = feat + ((size_t)b*D_ + c) * K_;
    const int* ib = idx + b*M_;
    float* grow = G + ((size_t)b*D_ + c) * M_;
    #pragma unroll
    for (int r = 0; r < 4; ++r) {
        int m = r*256 + t;
        grow[m] = frow[ib[m]];
    }
}

// ---------------------------------------------------------------------------
// fused LN: stats + apply + transpose -> xln bf16 [b][m][c]
// block = (b, 32 m's); grid (M/32, B)
__global__ __launch_bounds__(256) void k_ln_fused(const float* __restrict__ G,
                                                  const float* __restrict__ gamma,
                                                  const float* __restrict__ beta,
                                                  unsigned short* __restrict__ xln)
{
    int b = blockIdx.y, m0 = blockIdx.x * 32;
    int t = threadIdx.x;
    int ml = t & 31, cp = t >> 5;           // stats mapping
    const float* Gb = G + (size_t)b * D_ * M_;
    float s = 0.f, q = 0.f;
    for (int c = cp; c < D_; c += 8) {
        float v = Gb[(size_t)c*M_ + m0 + ml];
        s += v; q += v*v;
    }
    __shared__ float sred[8][32], qred[8][32];
    __shared__ float mu[32], iv[32];
    sred[cp][ml] = s; qred[cp][ml] = q;
    __syncthreads();
    if (t < 32) {
        float S = 0.f, Q = 0.f;
        #pragma unroll
        for (int r = 0; r < 8; ++r) { S += sred[r][t]; Q += qred[r][t]; }
        float m_ = S * (1.f/768.f);
        mu[t] = m_;
        iv[t] = rsqrtf(Q * (1.f/768.f) - m_*m_ + 1e-5f);
    }
    __syncthreads();

    __shared__ float tile[64][33];
    int ty = t >> 5;                        // 0..7
    int cx2 = t & 31;                       // c-pair index for writes
    for (int c0 = 0; c0 < D_; c0 += 64) {
        __syncthreads();
        #pragma unroll
        for (int ri = 0; ri < 8; ++ri) {
            int cl = ty*8 + ri;
            tile[cl][ml] = Gb[(size_t)(c0+cl)*M_ + m0 + ml];
        }
        __syncthreads();
        float2 ga = *(const float2*)&gamma[c0 + 2*cx2];
        float2 be = *(const float2*)&beta[c0 + 2*cx2];
        #pragma unroll
        for (int ri = 0; ri < 4; ++ri) {
            int m_l = ty*4 + ri;
            float v0 = (tile[2*cx2+0][m_l] - mu[m_l]) * iv[m_l] * ga.x + be.x;
            float v1 = (tile[2*cx2+1][m_l] - mu[m_l]) * iv[m_l] * ga.y + be.y;
            ushort2 pk = make_ushort2(f2bf(v0), f2bf(v1));
            *(ushort2*)&xln[((size_t)((b<<10) + m0 + m_l))*D_ + c0 + 2*cx2] = pk;
        }
    }
}

// ---------------------------------------------------------------------------
// seed_features [B][256][M] f32 -> fused[b][m][0:256] bf16 (row stride 512)
__global__ void k_transpose_sf(const float* __restrict__ sf,
                               unsigned short* __restrict__ fused)
{
    __shared__ float tile[32][33];
    int m0 = blockIdx.x*32, c0 = blockIdx.y*32, b = blockIdx.z;
    int tx = threadIdx.x, ty = threadIdx.y;
    #pragma unroll
    for (int r = 0; r < 32; r += 8)
        tile[ty+r][tx] = sf[((size_t)b*256 + c0+ty+r)*M_ + m0 + tx];
    __syncthreads();
    #pragma unroll
    for (int r = 0; r < 32; r += 8)
        fused[((size_t)(b*M_ + m0+ty+r))*512 + c0 + tx] = f2bf(tile[tx][ty+r]);
}

// ---------------------------------------------------------------------------
// weight conversions: Wb1=bf16(pw1); Wcat[:, :256]=bf16(fw1a); Wb4=bf16(fw2)
__global__ __launch_bounds__(256) void k_cvt(const float* __restrict__ pw1,
                                             const float* __restrict__ fw1,
                                             const float* __restrict__ fw2,
                                             unsigned short* __restrict__ Wb1,
                                             unsigned short* __restrict__ Wcat,
                                             unsigned short* __restrict__ Wb4)
{
    int i = blockIdx.x*256 + threadIdx.x;
    Wb1[i] = f2bf(pw1[i]);
    if (i < 65536) {
        int o = i >> 8, c = i & 255;
        Wcat[(size_t)o*512 + c] = f2bf(fw1[(size_t)o*512 + c]);
        Wb4[i] = f2bf(fw2[i]);
    }
}

// Wcat[:, 256:512] = bf16(fw1b @ pw2); bc = fw1b @ pb2 + fb1
__global__ __launch_bounds__(256) void k_wc(const float* __restrict__ fw1,
                                            const float* __restrict__ pw2,
                                            const float* __restrict__ pb2,
                                            const float* __restrict__ fb1,
                                            unsigned short* __restrict__ Wcat,
                                            float* __restrict__ bc)
{
    int o = blockIdx.x, t = threadIdx.x;
    const float* fb = fw1 + (size_t)o*512 + 256;
    float acc = 0.f;
    for (int j = 0; j < 256; ++j)
        acc = fmaf(fb[j], pw2[(size_t)j*256 + t], acc);
    Wcat[(size_t)o*512 + 256 + t] = f2bf(acc);
    float v = fb[t] * pb2[t];
    for (int off = 32; off; off >>= 1) v += __shfl_down(v, off, 64);
    __shared__ float red[4];
    if (!(t & 63)) red[t >> 6] = v;
    __syncthreads();
    if (!t) bc[o] = red[0]+red[1]+red[2]+red[3] + fb1[o];
}

// ---------------------------------------------------------------------------
// MFMA GEMM (round-1 verified): C[m][o] = act( X[m][:]·W[o][:] + bias[o] )
__global__ __launch_bounds__(256) void k_gemm_mfma(
    const unsigned short* __restrict__ X, const unsigned short* __restrict__ W,
    const float* __restrict__ bias, int Kdim, int relu, int mode,
    unsigned short* __restrict__ Ybf, int rowStride, int colOff,
    float* __restrict__ Yf)
{
    __shared__ unsigned short Al[64*64];
    __shared__ unsigned short Wl[64*64];
    int t = threadIdx.x, l = t & 63, w = t >> 6;
    int m0 = blockIdx.x * 64, o0 = blockIdx.y * 64;
    f32x4 acc[4];
    #pragma unroll
    for (int j = 0; j < 4; ++j) acc[j] = (f32x4){0.f, 0.f, 0.f, 0.f};

    for (int kc = 0; kc < Kdim; kc += 64) {
        #pragma unroll
        for (int i = 0; i < 2; ++i) {
            int lin = i*4096 + w*1024;
            int lb  = lin + l*16;
            int row = lb >> 7;
            int k16 = (lb >> 4) & 7;
            int ks  = k16 ^ (row & 7);
            gload_lds16(X + (size_t)(m0+row)*Kdim + kc + ks*8, (char*)Al + lin);
            gload_lds16(W + (size_t)(o0+row)*Kdim + kc + ks*8, (char*)Wl + lin);
        }
        __syncthreads();
        #pragma unroll
        for (int kk = 0; kk < 2; ++kk) {
            int arow = w*16 + (l & 15);
            int h = l >> 4;
            bf16x8 a = *(const bf16x8*)&Al[arow*64 + (((kk<<2)|h) ^ (arow & 7))*8];
            #pragma unroll
            for (int j = 0; j < 4; ++j) {
                int orow = j*16 + (l & 15);
                bf16x8 bfr = *(const bf16x8*)&Wl[orow*64 + (((kk<<2)|h) ^ (orow & 7))*8];
                acc[j] = __builtin_amdgcn_mfma_f32_16x16x32_bf16(a, bfr, acc[j], 0, 0, 0);
            }
        }
        __syncthreads();
    }

    int mbase = m0 + w*16 + (l >> 4)*4;
    if (mode == 0) {
        #pragma unroll
        for (int j = 0; j < 4; ++j) {
            int o = o0 + j*16 + (l & 15);
            float bi = bias[o];
            #pragma unroll
            for (int r = 0; r < 4; ++r) {
                float v = acc[j][r] + bi;
                if (relu) v = fmaxf(v, 0.f);
                Ybf[(size_t)(mbase + r)*rowStride + colOff + o] = f2bf(v);
            }
        }
    } else {
        int b = mbase >> 10, ml = mbase & 1023;
        #pragma unroll
        for (int j = 0; j < 4; ++j) {
            int o = o0 + j*16 + (l & 15);
            float bi = bias[o];
            float4 sv = make_float4(acc[j][0]+bi, acc[j][1]+bi, acc[j][2]+bi, acc[j][3]+bi);
            *(float4*)&Yf[((size_t)(b*256 + o))*1024 + ml] = sv;
        }
    }
}

// ---------------------------------------------------------------------------
extern "C" void kernel_launch(void* const* d_in, const int* in_sizes, int n_in,
                              void* d_out, int out_size, void* d_ws, size_t ws_size,
                              hipStream_t stream)
{
    (void)in_sizes; (void)n_in; (void)out_size; (void)ws_size;
    const float* pc        = (const float*)d_in[0];
    const float* seed_xyz  = (const float*)d_in[1];
    const float* seed_feat = (const float*)d_in[2];
    const float* pts       = (const float*)d_in[3];
    const float* feat      = (const float*)d_in[4];
    const float* ln_g      = (const float*)d_in[5];
    const float* ln_b      = (const float*)d_in[6];
    const float* pw1       = (const float*)d_in[7];
    const float* pb1       = (const float*)d_in[8];
    const float* pw2       = (const float*)d_in[9];
    const float* pb2       = (const float*)d_in[10];
    const float* fw1       = (const float*)d_in[11];
    const float* fb1       = (const float*)d_in[12];
    const float* fw2       = (const float*)d_in[13];
    const float* fb2       = (const float*)d_in[14];
    float* out = (float*)d_out;

    char* ws = (char*)d_ws;
    float*          part  = (float*)(ws + OFF_PART);
    float*          rad   = (float*)(ws + OFF_RAD);
    int*            idx   = (int*)(ws + OFF_IDX);
    float4*         P4    = (float4*)(ws + OFF_P4);
    float*          G     = (float*)(ws + OFF_G);
    unsigned short* xln   = (unsigned short*)(ws + OFF_XLN);
    unsigned short* fused = (unsigned short*)(ws + OFF_FUSED);
    unsigned short* h2    = (unsigned short*)(ws + OFF_H2);
    unsigned short* Wb1   = (unsigned short*)(ws + OFF_WB1);
    unsigned short* Wcat  = (unsigned short*)(ws + OFF_WCAT);
    unsigned short* Wb4   = (unsigned short*)(ws + OFF_WB4);
    float*          bc    = (float*)(ws + OFF_BC);

    k_cvt<<<768, 256, 0, stream>>>(pw1, fw1, fw2, Wb1, Wcat, Wb4);
    k_wc<<<256, 256, 0, stream>>>(fw1, pw2, pb2, fb1, Wcat, bc);
    k_cs_sum<<<64, 256, 0, stream>>>(pc, part);
    k_cs_rad<<<64, 256, 0, stream>>>(pc, part, rad);
    k_prep_pts<<<256, 256, 0, stream>>>(pts, part, rad, P4);
    k_nn<<<512, 256, 0, stream>>>(seed_xyz, P4, part, rad, idx);
    k_gather<<<dim3(D_, B_), 256, 0, stream>>>(feat, idx, G);
    k_ln_fused<<<dim3(M_/32, B_), 256, 0, stream>>>(G, ln_g, ln_b, xln);
    // gemm1: fused[:,256:512] = relu(pw1 @ xln + pb1)
    k_gemm_mfma<<<dim3(64, 4), 256, 0, stream>>>(xln, Wb1, pb1, 768, 1, 0, fused, 512, 256, nullptr);
    k_transpose_sf<<<dim3(M_/32, 256/32, B_), dim3(32, 8), 0, stream>>>(seed_feat, fused);
    // gemm3': h2 = relu(Wcat @ fused + bc)   (gemm2 algebraically folded in)
    k_gemm_mfma<<<dim3(64, 4), 256, 0, stream>>>(fused, Wcat, bc, 512, 1, 0, h2, 256, 0, nullptr);
    // gemm4: out = fw2 @ h2 + fb2 -> f32 [B][256][M]
    k_gemm_mfma<<<dim3(64, 4), 256, 0, stream>>>(h2, Wb4, fb2, 256, 0, 1, nullptr, 0, 0, out);
}